// Round 18
// baseline (187.848 us; speedup 1.0000x reference)
//
#include <hip/hip_runtime.h>
#include <hip/hip_bf16.h>
#include <cstdint>
#include <cmath>

// Problem constants
#define B_    2
#define S_    2048
#define HID_  2048
#define NH_   32
#define HD_   64
#define NQKV  34        // NH + 2
#define FDIM  2176      // NQKV * HD

typedef __attribute__((ext_vector_type(8)))  __bf16 bf16x8;
typedef __attribute__((ext_vector_type(4)))  float  f32x4;
typedef __attribute__((ext_vector_type(16))) float  f32x16;

__device__ __forceinline__ unsigned short f2bf(float f) {
  union { float f; uint32_t u; } v; v.f = f;
  return (unsigned short)((v.u + 0x7FFFu + ((v.u >> 16) & 1u)) >> 16);  // RNE
}
// pack two f32 -> u32 of 2 bf16 (compiler emits v_cvt_pk_bf16_f32 on gfx950)
__device__ __forceinline__ uint32_t pkbf(float lo, float hi) {
  union { __bf16 h[2]; uint32_t u; } z;
  z.h[0] = (__bf16)lo; z.h[1] = (__bf16)hi;
  return z.u;
}

// async global->LDS, 16B per lane. LDS dest is wave-uniform base + lane*16.
__device__ __forceinline__ void gload_lds16(const void* g, void* lds) {
  __builtin_amdgcn_global_load_lds(
      (const __attribute__((address_space(1))) uint32_t*)(uintptr_t)g,
      (__attribute__((address_space(3))) uint32_t*)(uint32_t)(uintptr_t)lds,
      16, 0, 0);
}

// swizzled LDS 16B read from a [rows][64] bf16 tile (128B rows), 2-level key:
// slot = ((c ^ (row&7)) + 2*((row>>3)&3)) & 7  -- the (row>>3) rotation spreads
// the 4 rows sharing row&7 across distinct bank groups (kills 4-way aliasing).
__device__ __forceinline__ bf16x8 lds_rd_swz(const unsigned short* tile, int row, int c) {
  return *reinterpret_cast<const bf16x8*>(
      reinterpret_cast<const char*>(tile) + row * 128 +
      ((((c ^ (row & 7)) + 2 * ((row >> 3) & 3)) & 7) << 4));
}

// ---------------- fp32 -> bf16 convert: all three inputs in ONE launch ----------------
#define N1Q (B_ * S_ * HID_ / 4)     // 2097152
#define N2Q (FDIM * HID_ / 4)        // 1114112
#define N3Q (HID_ * HID_ / 4)        // 1048576
__global__ void k_cvt_all(const float* __restrict__ a, const float* __restrict__ b,
                          const float* __restrict__ c,
                          unsigned short* __restrict__ oa, unsigned short* __restrict__ ob,
                          unsigned short* __restrict__ oc) {
  int i = blockIdx.x * blockDim.x + threadIdx.x;
  const float* src; unsigned short* dst; int off;
  if (i < N1Q)             { src = a; dst = oa; off = i; }
  else if (i < N1Q + N2Q)  { src = b; dst = ob; off = i - N1Q; }
  else if (i < N1Q + N2Q + N3Q) { src = c; dst = oc; off = i - N1Q - N2Q; }
  else return;
  float4 f = reinterpret_cast<const float4*>(src)[off];
  ushort4 o;
  o.x = f2bf(f.x); o.y = f2bf(f.y); o.z = f2bf(f.z); o.w = f2bf(f.w);
  reinterpret_cast<ushort4*>(dst)[off] = o;
}

// ---------------- GEMM1: fused = X @ Wqkv^T with RoPE epilogue ----------------
// BM=256, BN=128, BK=32; 512 threads = 8 waves (4M x 2N), wave tile 64x64.
// LDS 48 KB double-buffered; grid 272 (single round). Counted-vmcnt 2-phase.
// XCD swizzle (272 = 8*34).
__global__ __launch_bounds__(512, 4) void k_gemm1(const unsigned short* __restrict__ A,
                                                  const unsigned short* __restrict__ Bm,
                                                  unsigned short* __restrict__ Fb,
                                                  unsigned short* __restrict__ Kr,
                                                  unsigned short* __restrict__ Vt,
                                                  int M, int N, int K) {
  __shared__ __align__(16) char smem[49152];  // As[2]: 0/16K, Bs[2]: 32K/40K
  const int tid  = threadIdx.x;
  const int lane = tid & 63;
  const int w    = tid >> 6;
  const int wm   = w >> 1;        // 0..3 (M)
  const int wn   = w & 1;         // 0..1 (N)

  // XCD-aware block swizzle (bijective: nwg = 272 = 8*34)
  int flat = blockIdx.y * gridDim.x + blockIdx.x;
  const int cpx = (gridDim.x * gridDim.y) >> 3;
  flat = (flat & 7) * cpx + (flat >> 3);
  const int bn = flat % 17;
  const int bm = flat / 17;

  const unsigned short* gA = A  + (size_t)bm * 256 * K;
  const unsigned short* gB = Bm + (size_t)bn * 128 * K;

  // staging: each chunk = 8KB = 128 rows x 64B; thread t -> row u=t>>2, slot cq=t&3
  const int u  = tid >> 2;                       // 0..127
  const int cq = tid & 3;
  const int scol = (cq ^ ((u >> 1) & 3)) * 8;    // swizzled source elem offset
  const int gA0r = (u & 31) | ((u >> 5) << 6);   // chunk0 global row (bit5=0)
  const size_t rA0 = (size_t)gA0r * K + scol;
  const size_t rA1 = (size_t)(gA0r + 32) * K + scol;
  const size_t rB  = (size_t)u * K + scol;
  const int dOff = tid * 16;

  // frag-read byte offsets (chunking + swizzle folded in)
  const int kc = lane >> 4;   // 16B k-slot 0..3
  int offA[4], offB[4];
#pragma unroll
  for (int i = 0; i < 4; ++i) {
    int gr = wm * 64 + i * 16 + (lane & 15);
    int c  = (gr >> 5) & 1;
    int uu = (gr & 31) | ((gr >> 6) << 5);
    offA[i] = c * 8192 + uu * 64 + ((kc ^ ((uu >> 1) & 3)) << 4);
  }
#pragma unroll
  for (int j = 0; j < 4; ++j) {
    int br = wn * 64 + j * 16 + (lane & 15);
    offB[j] = br * 64 + ((kc ^ ((br >> 1) & 3)) << 4);
  }

  f32x4 acc[4][4] = {};
  const int NT = K >> 5;

  // prologue (tile 0, buf 0): order B, A0, A1
  gload_lds16(gB + rB,  smem + 32768 + dOff);
  gload_lds16(gA + rA0, smem + dOff);
  gload_lds16(gA + rA1, smem + 8192 + dOff);

  for (int t = 0; t < NT; ++t) {
    const char* Ac = smem + (t & 1) * 16384;
    const char* Bc = smem + 32768 + (t & 1) * 8192;
    char*       An = (char*)smem + ((t & 1) ^ 1) * 16384;
    char*       Bn = (char*)smem + 32768 + ((t & 1) ^ 1) * 8192;
    const size_t k1 = (size_t)(t + 1) << 5;
    const bool more = (t + 1 < NT);

    // ---- phase 0: A i=0,1 (chunk 0) + all B ----
    asm volatile("s_waitcnt vmcnt(1)" ::: "memory");
    __builtin_amdgcn_s_barrier();
    asm volatile("" ::: "memory");
    bf16x8 b0 = *(const bf16x8*)(Bc + offB[0]);
    bf16x8 b1 = *(const bf16x8*)(Bc + offB[1]);
    bf16x8 b2 = *(const bf16x8*)(Bc + offB[2]);
    bf16x8 b3 = *(const bf16x8*)(Bc + offB[3]);
    bf16x8 a0 = *(const bf16x8*)(Ac + offA[0]);
    bf16x8 a1 = *(const bf16x8*)(Ac + offA[1]);
    if (more) {
      gload_lds16(gB + rB + k1, Bn + dOff);
    }
    __builtin_amdgcn_s_setprio(1);
    acc[0][0] = __builtin_amdgcn_mfma_f32_16x16x32_bf16(a0, b0, acc[0][0], 0, 0, 0);
    acc[0][1] = __builtin_amdgcn_mfma_f32_16x16x32_bf16(a0, b1, acc[0][1], 0, 0, 0);
    acc[0][2] = __builtin_amdgcn_mfma_f32_16x16x32_bf16(a0, b2, acc[0][2], 0, 0, 0);
    acc[0][3] = __builtin_amdgcn_mfma_f32_16x16x32_bf16(a0, b3, acc[0][3], 0, 0, 0);
    acc[1][0] = __builtin_amdgcn_mfma_f32_16x16x32_bf16(a1, b0, acc[1][0], 0, 0, 0);
    acc[1][1] = __builtin_amdgcn_mfma_f32_16x16x32_bf16(a1, b1, acc[1][1], 0, 0, 0);
    acc[1][2] = __builtin_amdgcn_mfma_f32_16x16x32_bf16(a1, b2, acc[1][2], 0, 0, 0);
    acc[1][3] = __builtin_amdgcn_mfma_f32_16x16x32_bf16(a1, b3, acc[1][3], 0, 0, 0);
    __builtin_amdgcn_s_setprio(0);

    // ---- phase 1: A i=2,3 (chunk 1), B reused from registers ----
    if (more) { asm volatile("s_waitcnt vmcnt(1)" ::: "memory"); }
    else      { asm volatile("s_waitcnt vmcnt(0)" ::: "memory"); }
    __builtin_amdgcn_s_barrier();
    asm volatile("" ::: "memory");
    bf16x8 a2 = *(const bf16x8*)(Ac + offA[2]);
    bf16x8 a3 = *(const bf16x8*)(Ac + offA[3]);
    if (more) {
      gload_lds16(gA + rA0 + k1, An + dOff);
      gload_lds16(gA + rA1 + k1, An + 8192 + dOff);
    }
    __builtin_amdgcn_s_setprio(1);
    acc[2][0] = __builtin_amdgcn_mfma_f32_16x16x32_bf16(a2, b0, acc[2][0], 0, 0, 0);
    acc[2][1] = __builtin_amdgcn_mfma_f32_16x16x32_bf16(a2, b1, acc[2][1], 0, 0, 0);
    acc[2][2] = __builtin_amdgcn_mfma_f32_16x16x32_bf16(a2, b2, acc[2][2], 0, 0, 0);
    acc[2][3] = __builtin_amdgcn_mfma_f32_16x16x32_bf16(a2, b3, acc[2][3], 0, 0, 0);
    acc[3][0] = __builtin_amdgcn_mfma_f32_16x16x32_bf16(a3, b0, acc[3][0], 0, 0, 0);
    acc[3][1] = __builtin_amdgcn_mfma_f32_16x16x32_bf16(a3, b1, acc[3][1], 0, 0, 0);
    acc[3][2] = __builtin_amdgcn_mfma_f32_16x16x32_bf16(a3, b2, acc[3][2], 0, 0, 0);
    acc[3][3] = __builtin_amdgcn_mfma_f32_16x16x32_bf16(a3, b3, acc[3][3], 0, 0, 0);
    __builtin_amdgcn_s_setprio(0);
  }

  // ---- fused RoPE epilogue: pairs (j, j+2) = (i32, i32+32) within head h2 ----
  {
    const int rb = (lane >> 4) * 4;
    const int cb = lane & 15;
    const int h2 = bn * 2 + wn;
    const float QSCL = 0.18033688011112042f; // (1/8)*log2(e)
#pragma unroll
    for (int i = 0; i < 4; ++i) {
#pragma unroll
      for (int j = 0; j < 2; ++j) {
        const int i32 = j * 16 + cb;
        const float infr = expf(-(float)i32 * 0.2878231366242557f);  // 10000^(-i32/32)
#pragma unroll
        for (int r = 0; r < 4; ++r) {
          int row = bm * 256 + wm * 64 + i * 16 + rb + r;
          int s   = row & (S_ - 1);
          float o1 = acc[i][j][r], o2 = acc[i][j + 2][r];
          if (h2 <= NH_) {   // rope for Q heads + K head
            float sn, cs;
            sincosf((float)s * infr, &sn, &cs);
            float t1 = o1 * cs - o2 * sn;
            float t2 = o2 * cs + o1 * sn;
            o1 = t1; o2 = t2;
          }
          if (h2 < NH_) {          // Q: fold softmax scale, write to Fb
            unsigned short* p = Fb + (size_t)row * N + h2 * HD_;
            p[i32]      = f2bf(o1 * QSCL);
            p[i32 + 32] = f2bf(o2 * QSCL);
          } else if (h2 == NH_) {  // K head -> Kr
            Kr[(size_t)row * HD_ + i32]      = f2bf(o1);
            Kr[(size_t)row * HD_ + i32 + 32] = f2bf(o2);
          } else {                 // V head -> Vt transposed
            int bq = row >> 11;
            Vt[((size_t)(bq * HD_ + i32)) * S_ + s]      = f2bf(o1);
            Vt[((size_t)(bq * HD_ + i32 + 32)) * S_ + s] = f2bf(o2);
          }
        }
      }
    }
  }
}

// ---------------- GEMM2: out = ctx @ Wd^T (fp32 out), k-split, 16x16 ----------------
// BM=128, BN=128, BK=64; 512 threads = 8 waves; k-group wg owns k-half wg*32;
// 4 waves/group tile C 2Mx2N (64x64/wave). Counted-vmcnt 2-phase, A row-permuted
// (swap bits 5,6), chunk-XOR swizzle, symmetric LDS k-merge. 64KB LDS -> 2 blocks/CU.
// Grid 512 (16x32); XCD swizzle.
__global__ __launch_bounds__(512, 4) void k_gemm2(const unsigned short* __restrict__ A,
                                                  const unsigned short* __restrict__ Bm,
                                                  float* __restrict__ Cout,
                                                  int M, int N, int K) {
  __shared__ __align__(16) char smem[65536];
  const int tid  = threadIdx.x;
  const int lane = tid & 63;
  const int w    = tid >> 6;
  const int wg   = w >> 2;
  const int w2   = w & 3;
  const int wm   = w2 >> 1, wn = w2 & 1;

  int flat = blockIdx.y * gridDim.x + blockIdx.x;
  const int cpx = (gridDim.x * gridDim.y) >> 3;
  flat = (flat & 7) * cpx + (flat >> 3);
  const int bn = flat & 15;
  const int bm = flat >> 4;

  const unsigned short* gA = A  + (size_t)bm * 128 * K;
  const unsigned short* gB = Bm + (size_t)bn * 128 * K;

  const int su = tid >> 3;
  const int sx = tid & 7;
  const int scol = ((sx ^ (su & 7)) << 3);
  const int gA0r = (su & 31) | ((su & 32) << 1);
  const int gA1r = ((64 + su) & ~96) | (((64 + su) & 32) << 1) | (((64 + su) & 64) >> 1);
  const size_t rA0 = (size_t)gA0r * K + scol;
  const size_t rA1 = (size_t)gA1r * K + scol;
  const size_t rB0 = (size_t)(su) * K + scol;
  const size_t rB1 = (size_t)(64 + su) * K + scol;
  const int dOff = tid * 16;

  int offA[4], offB[4];
#pragma unroll
  for (int i = 0; i < 4; ++i) {
    int gr = wm * 64 + i * 16 + (lane & 15);
    int s  = (gr & ~96) | ((gr & 32) << 1) | ((gr & 64) >> 1);
    int n  = wg * 4 + (lane >> 4);
    offA[i] = s * 128 + ((n ^ (s & 7)) << 4);
  }
#pragma unroll
  for (int j = 0; j < 4; ++j) {
    int br = wn * 64 + j * 16 + (lane & 15);
    int n  = wg * 4 + (lane >> 4);
    offB[j] = br * 128 + ((n ^ (br & 7)) << 4);
  }

  f32x4 acc[4][4] = {};
  const int NT = K >> 6;

  gload_lds16(gB + rB0, smem + 32768 + dOff);
  gload_lds16(gB + rB1, smem + 40960 + dOff);
  gload_lds16(gA + rA0, smem + dOff);
  gload_lds16(gA + rA1, smem + 8192 + dOff);

  for (int t = 0; t < NT; ++t) {
    const char* Ac = smem + (t & 1) * 16384;
    const char* Bc = smem + 32768 + (t & 1) * 16384;
    char*       An = (char*)smem + ((t & 1) ^ 1) * 16384;
    char*       Bn = (char*)smem + 32768 + ((t & 1) ^ 1) * 16384;
    const size_t k1 = (size_t)(t + 1) << 6;
    const bool more = (t + 1 < NT);

    asm volatile("s_waitcnt vmcnt(1)" ::: "memory");
    __builtin_amdgcn_s_barrier();
    asm volatile("" ::: "memory");
    bf16x8 b0 = *(const bf16x8*)(Bc + offB[0]);
    bf16x8 b1 = *(const bf16x8*)(Bc + offB[1]);
    bf16x8 b2 = *(const bf16x8*)(Bc + offB[2]);
    bf16x8 b3 = *(const bf16x8*)(Bc + offB[3]);
    bf16x8 a0 = *(const bf16x8*)(Ac + offA[0]);
    bf16x8 a1 = *(const bf16x8*)(Ac + offA[1]);
    if (more) {
      gload_lds16(gB + rB0 + k1, Bn + dOff);
      gload_lds16(gB + rB1 + k1, Bn + 8192 + dOff);
    }
    __builtin_amdgcn_s_setprio(1);
    acc[0][0] = __builtin_amdgcn_mfma_f32_16x16x32_bf16(a0, b0, acc[0][0], 0, 0, 0);
    acc[0][1] = __builtin_amdgcn_mfma_f32_16x16x32_bf16(a0, b1, acc[0][1], 0, 0, 0);
    acc[0][2] = __builtin_amdgcn_mfma_f32_16x16x32_bf16(a0, b2, acc[0][2], 0, 0, 0);
    acc[0][3] = __builtin_amdgcn_mfma_f32_16x16x32_bf16(a0, b3, acc[0][3], 0, 0, 0);
    acc[1][0] = __builtin_amdgcn_mfma_f32_16x16x32_bf16(a1, b0, acc[1][0], 0, 0, 0);
    acc[1][1] = __builtin_amdgcn_mfma_f32_16x16x32_bf16(a1, b1, acc[1][1], 0, 0, 0);
    acc[1][2] = __builtin_amdgcn_mfma_f32_16x16x32_bf16(a1, b2, acc[1][2], 0, 0, 0);
    acc[1][3] = __builtin_amdgcn_mfma_f32_16x16x32_bf16(a1, b3, acc[1][3], 0, 0, 0);
    __builtin_amdgcn_s_setprio(0);

    if (more) { asm volatile("s_waitcnt vmcnt(2)" ::: "memory"); }
    else      { asm volatile("s_waitcnt vmcnt(0)" ::: "memory"); }
    __builtin_amdgcn_s_barrier();
    asm volatile("" ::: "memory");
    bf16x8 a2 = *(const bf16x8*)(Ac + offA[2]);
    bf16x8 a3 = *(const bf16x8*)(Ac + offA[3]);
    if (more) {
      gload_lds16(gA + rA0 + k1, An + dOff);
      gload_lds16(gA + rA1 + k1, An + 8192 + dOff);
    }
    __builtin_amdgcn_s_setprio(1);
    acc[2][0] = __builtin_amdgcn_mfma_f32_16x16x32_bf16(a2, b0, acc[2][0], 0, 0, 0);
    acc[2][1] = __builtin_amdgcn_mfma_f32_16x16x32_bf16(a2, b1, acc[2][1], 0, 0, 0);
    acc[2][2] = __builtin_amdgcn_mfma_f32_16x16x32_bf16(a2, b2, acc[2][2], 0, 0, 0);
    acc[2][3] = __builtin_amdgcn_mfma_f32_16x16x32_bf16(a2, b3, acc[2][3], 0, 0, 0);
    acc[3][0] = __builtin_amdgcn_mfma_f32_16x16x32_bf16(a3, b0, acc[3][0], 0, 0, 0);
    acc[3][1] = __builtin_amdgcn_mfma_f32_16x16x32_bf16(a3, b1, acc[3][1], 0, 0, 0);
    acc[3][2] = __builtin_amdgcn_mfma_f32_16x16x32_bf16(a3, b2, acc[3][2], 0, 0, 0);
    acc[3][3] = __builtin_amdgcn_mfma_f32_16x16x32_bf16(a3, b3, acc[3][3], 0, 0, 0);
    __builtin_amdgcn_s_setprio(0);
  }

  __syncthreads();
  {
    float* pub = (float*)(smem + wg * 32768);
#pragma unroll
    for (int ii = 0; ii < 2; ++ii) {
      const int ip = wg ? ii : 2 + ii;
#pragma unroll
      for (int j = 0; j < 4; ++j)
#pragma unroll
        for (int r = 0; r < 4; ++r)
          pub[((ii * 4 + j) * 4 + r) * 256 + w2 * 64 + lane] = acc[ip][j][r];
    }
  }
  __syncthreads();
  {
    const float* oth = (const float*)(smem + (wg ^ 1) * 32768);
    const int rb = (lane >> 4) * 4;
    const int cb = lane & 15;
#pragma unroll
    for (int ii = 0; ii < 2; ++ii) {
      const int im = wg ? 2 + ii : ii;
#pragma unroll
      for (int j = 0; j < 4; ++j)
#pragma unroll
        for (int r = 0; r < 4; ++r) {
          float vsum = acc[im][j][r] + oth[((ii * 4 + j) * 4 + r) * 256 + w2 * 64 + lane];
          int row = bm * 128 + wm * 64 + im * 16 + rb + r;
          int col = bn * 128 + wn * 64 + j * 16 + cb;
          Cout[(size_t)row * N + col] = vsum;
        }
    }
  }
}

// ---------------- causal flash attention (MQA), kv-split wave pairs ----------------
// grid (8, B*NH) = 512 blocks (exactly 2/CU). block 512 = 8 waves = 4 pairs.
// Pair p owns 32 q rows; wave hw=w&1 handles kv rows [hw*32, hw*32+32) of each
// 64-row KV tile. K/V LDS uses the 2-level swizzle (kills the 4-way aliasing of
// the 32-lane row-column reads); staging source applies the inverse permutation.
__global__ __launch_bounds__(512) void k_attn(const unsigned short* __restrict__ fused,
                                              const unsigned short* __restrict__ Kr,
                                              const unsigned short* __restrict__ Vt,
                                              unsigned short* __restrict__ ctx) {
  __shared__ unsigned short Ks[2][64 * 64];  // 16 KB, swizzled
  __shared__ unsigned short Vs[2][64 * 64];  // 16 KB, swizzled
  __shared__ float Scr[4][64][35];           // pair-merge scratch, stride 35 (bank spread)
  const int tid  = threadIdx.x;
  const int lane = tid & 63;
  const int w    = tid >> 6;      // 0..7
  const int p    = w >> 1;        // pair 0..3
  const int hw   = w & 1;         // kv half
  const int pr   = blockIdx.x;    // 0..7
  const int bh   = blockIdx.y;
  const int b    = bh >> 5;
  const int h    = bh & 31;
  const int ql   = lane & 31;
  const int hi   = lane >> 5;

  // staging: thread t -> LDS row strow=t>>3, slot stch=t&7 (dest linear t*16).
  // inverse of the 2-level read swizzle: chunk c = ((slot - 2*((row>>3)&3)) & 7) ^ (row&7)
  const int strow = tid >> 3;                 // 0..63
  const int stch  = tid & 7;
  const int ssc   = (((stch - 2 * ((strow >> 3) & 3)) & 7) ^ (strow & 7)) * 8;
  const size_t kSrc = (size_t)(b * S_ + strow) * HD_ + ssc;
  const size_t vSrc = (size_t)(b * HD_ + strow) * S_ + ssc;
  const int dOff = tid * 16;

  for (int side = 0; side < 2; ++side) {
    const int qt = side ? (15 - pr) : pr;
    const int q0 = qt * 128;
    const int nt = 2 * qt + 2;
    const int qrow  = q0 + p * 32 + ql;
    const int qlo_w = q0 + p * 32;
    const int qhi_w = qlo_w + 31;

    bf16x8 qf[4];
    {
      const unsigned short* qb =
          fused + ((size_t)(b * S_ + qrow)) * FDIM + h * HD_ + hi * 8;
#pragma unroll
      for (int s = 0; s < 4; ++s)
        qf[s] = *reinterpret_cast<const bf16x8*>(qb + s * 16);
    }

    f32x16 oacc0 = {}, oacc1 = {}, lsumv = {};
    float mrun = -1e30f;

    if (side) __syncthreads();

    gload_lds16(Kr + kSrc, (char*)Ks + dOff);
    gload_lds16(Vt + vSrc, (char*)Vs + dOff);

    int buf = 0;
    for (int t = 0; t < nt; ++t) {
      __syncthreads();

      if (t + 1 < nt) {
        const int kv1 = (t + 1) * 64;
        gload_lds16(Kr + kSrc + (size_t)kv1 * HD_, (char*)Ks + (buf ^ 1) * 8192 + dOff);
        gload_lds16(Vt + vSrc + kv1,               (char*)Vs + (buf ^ 1) * 8192 + dOff);
      }

      const int kv0 = t * 64;
      const unsigned short* Kcur = (const unsigned short*)((const char*)Ks + buf * 8192);
      const unsigned short* Vcur = (const unsigned short*)((const char*)Vs + buf * 8192);
      buf ^= 1;

      if (kv0 + hw * 32 > qhi_w) continue;

      f32x16 sh = {};
      __builtin_amdgcn_s_setprio(1);
#pragma unroll
      for (int s = 0; s < 4; ++s) {
        bf16x8 kf = lds_rd_swz(Kcur, hw * 32 + ql, s * 2 + hi);
        sh = __builtin_amdgcn_mfma_f32_32x32x16_bf16(kf, qf[s], sh, 0, 0, 0);
      }
      __builtin_amdgcn_s_setprio(0);

      if (kv0 + hw * 32 + 31 > qlo_w) {
        const int thr = qrow - kv0 - hw * 32 - 4 * hi;
#pragma unroll
        for (int r = 0; r < 16; ++r) {
          const int kvo = (r & 3) + 8 * (r >> 2);
          sh[r] = (kvo <= thr) ? sh[r] : -1e30f;
        }
      }

      float mx;
      {
        float t16[8];
#pragma unroll
        for (int r = 0; r < 8; ++r) t16[r] = fmaxf(sh[r], sh[r + 8]);
#pragma unroll
        for (int st = 4; st >= 1; st >>= 1)
#pragma unroll
          for (int r = 0; r < st; ++r) t16[r] = fmaxf(t16[r], t16[r + st]);
        mx = fmaxf(t16[0], __shfl_xor(t16[0], 32));
      }

      float mcur;
      bool okd = (mx <= mrun + 8.0f);
      if (__all(okd)) {
        mcur = mrun;
      } else {
        float mnew = fmaxf(mrun, mx);
        float corr = __builtin_amdgcn_exp2f(mrun - mnew);
        mrun = mnew; mcur = mnew;
#pragma unroll
        for (int r = 0; r < 16; ++r) {
          oacc0[r] *= corr; oacc1[r] *= corr; lsumv[r] *= corr;
        }
      }

#pragma unroll
      for (int r = 0; r < 16; ++r) {
        sh[r] = __builtin_amdgcn_exp2f(sh[r] - mcur);
        lsumv[r] += sh[r];
      }

      bf16x8 pf[2];
#pragma unroll
      for (int j = 0; j < 2; ++j) {
        uint32_t a0 = pkbf(sh[8 * j + 0], sh[8 * j + 1]);
        uint32_t a1 = pkbf(sh[8 * j + 2], sh[8 * j + 3]);
        uint32_t b0 = pkbf(sh[8 * j + 4], sh[8 * j + 5]);
        uint32_t b1 = pkbf(sh[8 * j + 6], sh[8 * j + 7]);
        uint32_t s0 = hi ? a0 : b0;
        uint32_t s1 = hi ? a1 : b1;
        uint32_t r0 = __shfl_xor(s0, 32);
        uint32_t r1 = __shfl_xor(s1, 32);
        union { uint32_t wd[4]; bf16x8 v; } bw;
        bw.wd[0] = hi ? r0 : a0;
        bw.wd[1] = hi ? r1 : a1;
        bw.wd[2] = hi ? b0 : r0;
        bw.wd[3] = hi ? b1 : r1;
        pf[j] = bw.v;
      }

      __builtin_amdgcn_s_setprio(1);
#pragma unroll
      for (int j = 0; j < 2; ++j) {
        bf16x8 vf0 = lds_rd_swz(Vcur, ql,      hw * 4 + j * 2 + hi);
        bf16x8 vf1 = lds_rd_swz(Vcur, 32 + ql, hw * 4 + j * 2 + hi);
        oacc0 = __builtin_amdgcn_mfma_f32_32x32x16_bf16(vf0, pf[j], oacc0, 0, 0, 0);
        oacc1 = __builtin_amdgcn_mfma_f32_32x32x16_bf16(vf1, pf[j], oacc1, 0, 0, 0);
      }
      __builtin_amdgcn_s_setprio(0);
    }

    float lw;
    {
      float t16[8];
#pragma unroll
      for (int r = 0; r < 8; ++r) t16[r] = lsumv[r] + lsumv[r + 8];
#pragma unroll
      for (int st = 4; st >= 1; st >>= 1)
#pragma unroll
        for (int r = 0; r < st; ++r) t16[r] += t16[r + st];
      lw = t16[0] + __shfl_xor(t16[0], 32);
    }

    if (hw) {
      float* sp = &Scr[p][lane][0];
#pragma unroll
      for (int r = 0; r < 16; ++r) { sp[r] = oacc0[r]; sp[16 + r] = oacc1[r]; }
      sp[32] = mrun; sp[33] = lw;
    }
    __syncthreads();
    if (!hw) {
      const float* sp = &Scr[p][lane][0];
      float m1 = sp[32], l1 = sp[33];
      float m  = fmaxf(mrun, m1);
      float c0 = __builtin_amdgcn_exp2f(mrun - m);
      float c1 = __builtin_amdgcn_exp2f(m1 - m);
      float inv = 1.0f / (lw * c0 + l1 * c1);
      unsigned short* cb = ctx + ((size_t)(b * S_ + qrow)) * HID_ + h * HD_;
#pragma unroll
      for (int dblk = 0; dblk < 2; ++dblk) {
#pragma unroll
        for (int r = 0; r < 16; r += 2) {
          float own0 = dblk ? oacc1[r]     : oacc0[r];
          float own1 = dblk ? oacc1[r + 1] : oacc0[r + 1];
          float e0 = (own0 * c0 + sp[dblk * 16 + r]     * c1) * inv;
          float e1 = (own1 * c0 + sp[dblk * 16 + r + 1] * c1) * inv;
          int d = dblk * 32 + (r & 3) + 8 * (r >> 2) + 4 * hi;
          *reinterpret_cast<uint32_t*>(cb + d) = pkbf(e0, e1);
        }
      }
    }
  }
}

// ---------------- launch ----------------
extern "C" void kernel_launch(void* const* d_in, const int* in_sizes, int n_in,
                              void* d_out, int out_size, void* d_ws, size_t ws_size,
                              hipStream_t stream) {
  const float* hidden  = (const float*)d_in[0];
  const float* w_qkv   = (const float*)d_in[1];
  const float* w_dense = (const float*)d_in[2];
  char* ws = (char*)d_ws;

  // workspace layout (bytes)
  unsigned short* Xb  = (unsigned short*)(ws + 0);          // 4096x2048 bf16 (reused as ctx)
  unsigned short* Wqb = (unsigned short*)(ws + 16777216);   // 2176x2048 bf16
  unsigned short* Wdb = (unsigned short*)(ws + 25690112);   // 2048x2048 bf16
  unsigned short* Fb  = (unsigned short*)(ws + 34078720);   // 4096x2176 bf16 (fused QKV)
  unsigned short* Kr  = (unsigned short*)(ws + 51904512);   // 2x2048x64 bf16
  unsigned short* Vt  = (unsigned short*)(ws + 52428800);   // 2x64x2048 bf16

  // all three fp32->bf16 converts in one launch
  const int nq = N1Q + N2Q + N3Q;   // 4259840 float4 groups
  k_cvt_all<<<dim3((nq + 255) / 256), 256, 0, stream>>>(
      hidden, w_qkv, w_dense, Xb, Wqb, Wdb);

  // fused = X @ Wqkv^T with fused RoPE epilogue. grid (17,16) = 272, XCD-swizzled
  k_gemm1<<<dim3(FDIM / 128, (B_ * S_) / 256), 512, 0, stream>>>(
      Xb, Wqb, Fb, Kr, Vt, B_ * S_, FDIM, HID_);

  // attention -> ctx (reuses Xb)
  k_attn<<<dim3(8, B_ * NH_), 512, 0, stream>>>(Fb, Kr, Vt, Xb);

  // out = ctx @ Wd^T, fp32. grid (16,32) = 512 = exactly 2 blocks/CU, XCD-swizzled
  k_gemm2<<<dim3(HID_ / 128, (B_ * S_) / 128), 512, 0, stream>>>(
      Xb, Wdb, (float*)d_out, B_ * S_, HID_, HID_);
}

// Round 19
// 182.705 us; speedup vs baseline: 1.0281x; 1.0281x over previous
//
#include <hip/hip_runtime.h>
#include <hip/hip_bf16.h>
#include <cstdint>
#include <cmath>

// Problem constants
#define B_    2
#define S_    2048
#define HID_  2048
#define NH_   32
#define HD_   64
#define NQKV  34        // NH + 2
#define FDIM  2176      // NQKV * HD

typedef __attribute__((ext_vector_type(8)))  __bf16 bf16x8;
typedef __attribute__((ext_vector_type(4)))  float  f32x4;
typedef __attribute__((ext_vector_type(16))) float  f32x16;

__device__ __forceinline__ unsigned short f2bf(float f) {
  union { float f; uint32_t u; } v; v.f = f;
  return (unsigned short)((v.u + 0x7FFFu + ((v.u >> 16) & 1u)) >> 16);  // RNE
}
// pack two f32 -> u32 of 2 bf16 (compiler emits v_cvt_pk_bf16_f32 on gfx950)
__device__ __forceinline__ uint32_t pkbf(float lo, float hi) {
  union { __bf16 h[2]; uint32_t u; } z;
  z.h[0] = (__bf16)lo; z.h[1] = (__bf16)hi;
  return z.u;
}

// async global->LDS, 16B per lane. LDS dest is wave-uniform base + lane*16.
__device__ __forceinline__ void gload_lds16(const void* g, void* lds) {
  __builtin_amdgcn_global_load_lds(
      (const __attribute__((address_space(1))) uint32_t*)(uintptr_t)g,
      (__attribute__((address_space(3))) uint32_t*)(uint32_t)(uintptr_t)lds,
      16, 0, 0);
}

// swizzled LDS 16B read from a [rows][64] bf16 tile (128B rows):
// chunk c in [0,8), actual chunk = c ^ (row&7)   (optimal for this geometry)
__device__ __forceinline__ bf16x8 lds_rd_swz(const unsigned short* tile, int row, int c) {
  return *reinterpret_cast<const bf16x8*>(
      reinterpret_cast<const char*>(tile) + row * 128 + ((c ^ (row & 7)) << 4));
}

// ---------------- fp32 -> bf16 convert: all three inputs in ONE launch ----------------
#define N1Q (B_ * S_ * HID_ / 4)     // 2097152
#define N2Q (FDIM * HID_ / 4)        // 1114112
#define N3Q (HID_ * HID_ / 4)        // 1048576
__global__ void k_cvt_all(const float* __restrict__ a, const float* __restrict__ b,
                          const float* __restrict__ c,
                          unsigned short* __restrict__ oa, unsigned short* __restrict__ ob,
                          unsigned short* __restrict__ oc) {
  int i = blockIdx.x * blockDim.x + threadIdx.x;
  const float* src; unsigned short* dst; int off;
  if (i < N1Q)             { src = a; dst = oa; off = i; }
  else if (i < N1Q + N2Q)  { src = b; dst = ob; off = i - N1Q; }
  else if (i < N1Q + N2Q + N3Q) { src = c; dst = oc; off = i - N1Q - N2Q; }
  else return;
  float4 f = reinterpret_cast<const float4*>(src)[off];
  ushort4 o;
  o.x = f2bf(f.x); o.y = f2bf(f.y); o.z = f2bf(f.z); o.w = f2bf(f.w);
  reinterpret_cast<ushort4*>(dst)[off] = o;
}

// ---------------- GEMM1: fused = X @ Wqkv^T with RoPE epilogue ----------------
// BM=256, BN=128, BK=32; 512 threads = 8 waves (4M x 2N), wave tile 64x64.
// LDS 48 KB double-buffered; grid 272 (single round). Counted-vmcnt 2-phase.
// XCD swizzle (272 = 8*34).
__global__ __launch_bounds__(512, 4) void k_gemm1(const unsigned short* __restrict__ A,
                                                  const unsigned short* __restrict__ Bm,
                                                  unsigned short* __restrict__ Fb,
                                                  unsigned short* __restrict__ Kr,
                                                  unsigned short* __restrict__ Vt,
                                                  int M, int N, int K) {
  __shared__ __align__(16) char smem[49152];  // As[2]: 0/16K, Bs[2]: 32K/40K
  const int tid  = threadIdx.x;
  const int lane = tid & 63;
  const int w    = tid >> 6;
  const int wm   = w >> 1;        // 0..3 (M)
  const int wn   = w & 1;         // 0..1 (N)

  // XCD-aware block swizzle (bijective: nwg = 272 = 8*34)
  int flat = blockIdx.y * gridDim.x + blockIdx.x;
  const int cpx = (gridDim.x * gridDim.y) >> 3;
  flat = (flat & 7) * cpx + (flat >> 3);
  const int bn = flat % 17;
  const int bm = flat / 17;

  const unsigned short* gA = A  + (size_t)bm * 256 * K;
  const unsigned short* gB = Bm + (size_t)bn * 128 * K;

  // staging: each chunk = 8KB = 128 rows x 64B; thread t -> row u=t>>2, slot cq=t&3
  const int u  = tid >> 2;                       // 0..127
  const int cq = tid & 3;
  const int scol = (cq ^ ((u >> 1) & 3)) * 8;    // swizzled source elem offset
  const int gA0r = (u & 31) | ((u >> 5) << 6);   // chunk0 global row (bit5=0)
  const size_t rA0 = (size_t)gA0r * K + scol;
  const size_t rA1 = (size_t)(gA0r + 32) * K + scol;
  const size_t rB  = (size_t)u * K + scol;
  const int dOff = tid * 16;

  // frag-read byte offsets (chunking + swizzle folded in)
  const int kc = lane >> 4;   // 16B k-slot 0..3
  int offA[4], offB[4];
#pragma unroll
  for (int i = 0; i < 4; ++i) {
    int gr = wm * 64 + i * 16 + (lane & 15);
    int c  = (gr >> 5) & 1;
    int uu = (gr & 31) | ((gr >> 6) << 5);
    offA[i] = c * 8192 + uu * 64 + ((kc ^ ((uu >> 1) & 3)) << 4);
  }
#pragma unroll
  for (int j = 0; j < 4; ++j) {
    int br = wn * 64 + j * 16 + (lane & 15);
    offB[j] = br * 64 + ((kc ^ ((br >> 1) & 3)) << 4);
  }

  f32x4 acc[4][4] = {};
  const int NT = K >> 5;

  // prologue (tile 0, buf 0): order B, A0, A1
  gload_lds16(gB + rB,  smem + 32768 + dOff);
  gload_lds16(gA + rA0, smem + dOff);
  gload_lds16(gA + rA1, smem + 8192 + dOff);

  for (int t = 0; t < NT; ++t) {
    const char* Ac = smem + (t & 1) * 16384;
    const char* Bc = smem + 32768 + (t & 1) * 8192;
    char*       An = (char*)smem + ((t & 1) ^ 1) * 16384;
    char*       Bn = (char*)smem + 32768 + ((t & 1) ^ 1) * 8192;
    const size_t k1 = (size_t)(t + 1) << 5;
    const bool more = (t + 1 < NT);

    // ---- phase 0: A i=0,1 (chunk 0) + all B ----
    asm volatile("s_waitcnt vmcnt(1)" ::: "memory");
    __builtin_amdgcn_s_barrier();
    asm volatile("" ::: "memory");
    bf16x8 b0 = *(const bf16x8*)(Bc + offB[0]);
    bf16x8 b1 = *(const bf16x8*)(Bc + offB[1]);
    bf16x8 b2 = *(const bf16x8*)(Bc + offB[2]);
    bf16x8 b3 = *(const bf16x8*)(Bc + offB[3]);
    bf16x8 a0 = *(const bf16x8*)(Ac + offA[0]);
    bf16x8 a1 = *(const bf16x8*)(Ac + offA[1]);
    if (more) {
      gload_lds16(gB + rB + k1, Bn + dOff);
    }
    __builtin_amdgcn_s_setprio(1);
    acc[0][0] = __builtin_amdgcn_mfma_f32_16x16x32_bf16(a0, b0, acc[0][0], 0, 0, 0);
    acc[0][1] = __builtin_amdgcn_mfma_f32_16x16x32_bf16(a0, b1, acc[0][1], 0, 0, 0);
    acc[0][2] = __builtin_amdgcn_mfma_f32_16x16x32_bf16(a0, b2, acc[0][2], 0, 0, 0);
    acc[0][3] = __builtin_amdgcn_mfma_f32_16x16x32_bf16(a0, b3, acc[0][3], 0, 0, 0);
    acc[1][0] = __builtin_amdgcn_mfma_f32_16x16x32_bf16(a1, b0, acc[1][0], 0, 0, 0);
    acc[1][1] = __builtin_amdgcn_mfma_f32_16x16x32_bf16(a1, b1, acc[1][1], 0, 0, 0);
    acc[1][2] = __builtin_amdgcn_mfma_f32_16x16x32_bf16(a1, b2, acc[1][2], 0, 0, 0);
    acc[1][3] = __builtin_amdgcn_mfma_f32_16x16x32_bf16(a1, b3, acc[1][3], 0, 0, 0);
    __builtin_amdgcn_s_setprio(0);

    // ---- phase 1: A i=2,3 (chunk 1), B reused from registers ----
    if (more) { asm volatile("s_waitcnt vmcnt(1)" ::: "memory"); }
    else      { asm volatile("s_waitcnt vmcnt(0)" ::: "memory"); }
    __builtin_amdgcn_s_barrier();
    asm volatile("" ::: "memory");
    bf16x8 a2 = *(const bf16x8*)(Ac + offA[2]);
    bf16x8 a3 = *(const bf16x8*)(Ac + offA[3]);
    if (more) {
      gload_lds16(gA + rA0 + k1, An + dOff);
      gload_lds16(gA + rA1 + k1, An + 8192 + dOff);
    }
    __builtin_amdgcn_s_setprio(1);
    acc[2][0] = __builtin_amdgcn_mfma_f32_16x16x32_bf16(a2, b0, acc[2][0], 0, 0, 0);
    acc[2][1] = __builtin_amdgcn_mfma_f32_16x16x32_bf16(a2, b1, acc[2][1], 0, 0, 0);
    acc[2][2] = __builtin_amdgcn_mfma_f32_16x16x32_bf16(a2, b2, acc[2][2], 0, 0, 0);
    acc[2][3] = __builtin_amdgcn_mfma_f32_16x16x32_bf16(a2, b3, acc[2][3], 0, 0, 0);
    acc[3][0] = __builtin_amdgcn_mfma_f32_16x16x32_bf16(a3, b0, acc[3][0], 0, 0, 0);
    acc[3][1] = __builtin_amdgcn_mfma_f32_16x16x32_bf16(a3, b1, acc[3][1], 0, 0, 0);
    acc[3][2] = __builtin_amdgcn_mfma_f32_16x16x32_bf16(a3, b2, acc[3][2], 0, 0, 0);
    acc[3][3] = __builtin_amdgcn_mfma_f32_16x16x32_bf16(a3, b3, acc[3][3], 0, 0, 0);
    __builtin_amdgcn_s_setprio(0);
  }

  // ---- fused RoPE epilogue: pairs (j, j+2) = (i32, i32+32) within head h2 ----
  {
    const int rb = (lane >> 4) * 4;
    const int cb = lane & 15;
    const int h2 = bn * 2 + wn;
    const float QSCL = 0.18033688011112042f; // (1/8)*log2(e)
#pragma unroll
    for (int i = 0; i < 4; ++i) {
#pragma unroll
      for (int j = 0; j < 2; ++j) {
        const int i32 = j * 16 + cb;
        const float infr = expf(-(float)i32 * 0.2878231366242557f);  // 10000^(-i32/32)
#pragma unroll
        for (int r = 0; r < 4; ++r) {
          int row = bm * 256 + wm * 64 + i * 16 + rb + r;
          int s   = row & (S_ - 1);
          float o1 = acc[i][j][r], o2 = acc[i][j + 2][r];
          if (h2 <= NH_) {   // rope for Q heads + K head
            float sn, cs;
            sincosf((float)s * infr, &sn, &cs);
            float t1 = o1 * cs - o2 * sn;
            float t2 = o2 * cs + o1 * sn;
            o1 = t1; o2 = t2;
          }
          if (h2 < NH_) {          // Q: fold softmax scale, write to Fb
            unsigned short* p = Fb + (size_t)row * N + h2 * HD_;
            p[i32]      = f2bf(o1 * QSCL);
            p[i32 + 32] = f2bf(o2 * QSCL);
          } else if (h2 == NH_) {  // K head -> Kr
            Kr[(size_t)row * HD_ + i32]      = f2bf(o1);
            Kr[(size_t)row * HD_ + i32 + 32] = f2bf(o2);
          } else {                 // V head -> Vt transposed
            int bq = row >> 11;
            Vt[((size_t)(bq * HD_ + i32)) * S_ + s]      = f2bf(o1);
            Vt[((size_t)(bq * HD_ + i32 + 32)) * S_ + s] = f2bf(o2);
          }
        }
      }
    }
  }
}

// ---------------- GEMM2: out = ctx @ Wd^T (fp32 out), k-split, 16x16 ----------------
// BM=128, BN=128, BK=64; 512 threads = 8 waves; k-group wg owns k-half wg*32;
// 4 waves/group tile C 2Mx2N (64x64/wave). Counted-vmcnt 2-phase, A row-permuted
// (swap bits 5,6), chunk-XOR swizzle, symmetric LDS k-merge. 64KB LDS -> 2 blocks/CU.
// Grid 512 (16x32); XCD swizzle.
__global__ __launch_bounds__(512, 4) void k_gemm2(const unsigned short* __restrict__ A,
                                                  const unsigned short* __restrict__ Bm,
                                                  float* __restrict__ Cout,
                                                  int M, int N, int K) {
  __shared__ __align__(16) char smem[65536];
  const int tid  = threadIdx.x;
  const int lane = tid & 63;
  const int w    = tid >> 6;
  const int wg   = w >> 2;
  const int w2   = w & 3;
  const int wm   = w2 >> 1, wn = w2 & 1;

  int flat = blockIdx.y * gridDim.x + blockIdx.x;
  const int cpx = (gridDim.x * gridDim.y) >> 3;
  flat = (flat & 7) * cpx + (flat >> 3);
  const int bn = flat & 15;
  const int bm = flat >> 4;

  const unsigned short* gA = A  + (size_t)bm * 128 * K;
  const unsigned short* gB = Bm + (size_t)bn * 128 * K;

  const int su = tid >> 3;
  const int sx = tid & 7;
  const int scol = ((sx ^ (su & 7)) << 3);
  const int gA0r = (su & 31) | ((su & 32) << 1);
  const int gA1r = ((64 + su) & ~96) | (((64 + su) & 32) << 1) | (((64 + su) & 64) >> 1);
  const size_t rA0 = (size_t)gA0r * K + scol;
  const size_t rA1 = (size_t)gA1r * K + scol;
  const size_t rB0 = (size_t)(su) * K + scol;
  const size_t rB1 = (size_t)(64 + su) * K + scol;
  const int dOff = tid * 16;

  int offA[4], offB[4];
#pragma unroll
  for (int i = 0; i < 4; ++i) {
    int gr = wm * 64 + i * 16 + (lane & 15);
    int s  = (gr & ~96) | ((gr & 32) << 1) | ((gr & 64) >> 1);
    int n  = wg * 4 + (lane >> 4);
    offA[i] = s * 128 + ((n ^ (s & 7)) << 4);
  }
#pragma unroll
  for (int j = 0; j < 4; ++j) {
    int br = wn * 64 + j * 16 + (lane & 15);
    int n  = wg * 4 + (lane >> 4);
    offB[j] = br * 128 + ((n ^ (br & 7)) << 4);
  }

  f32x4 acc[4][4] = {};
  const int NT = K >> 6;

  gload_lds16(gB + rB0, smem + 32768 + dOff);
  gload_lds16(gB + rB1, smem + 40960 + dOff);
  gload_lds16(gA + rA0, smem + dOff);
  gload_lds16(gA + rA1, smem + 8192 + dOff);

  for (int t = 0; t < NT; ++t) {
    const char* Ac = smem + (t & 1) * 16384;
    const char* Bc = smem + 32768 + (t & 1) * 16384;
    char*       An = (char*)smem + ((t & 1) ^ 1) * 16384;
    char*       Bn = (char*)smem + 32768 + ((t & 1) ^ 1) * 16384;
    const size_t k1 = (size_t)(t + 1) << 6;
    const bool more = (t + 1 < NT);

    asm volatile("s_waitcnt vmcnt(1)" ::: "memory");
    __builtin_amdgcn_s_barrier();
    asm volatile("" ::: "memory");
    bf16x8 b0 = *(const bf16x8*)(Bc + offB[0]);
    bf16x8 b1 = *(const bf16x8*)(Bc + offB[1]);
    bf16x8 b2 = *(const bf16x8*)(Bc + offB[2]);
    bf16x8 b3 = *(const bf16x8*)(Bc + offB[3]);
    bf16x8 a0 = *(const bf16x8*)(Ac + offA[0]);
    bf16x8 a1 = *(const bf16x8*)(Ac + offA[1]);
    if (more) {
      gload_lds16(gB + rB0 + k1, Bn + dOff);
      gload_lds16(gB + rB1 + k1, Bn + 8192 + dOff);
    }
    __builtin_amdgcn_s_setprio(1);
    acc[0][0] = __builtin_amdgcn_mfma_f32_16x16x32_bf16(a0, b0, acc[0][0], 0, 0, 0);
    acc[0][1] = __builtin_amdgcn_mfma_f32_16x16x32_bf16(a0, b1, acc[0][1], 0, 0, 0);
    acc[0][2] = __builtin_amdgcn_mfma_f32_16x16x32_bf16(a0, b2, acc[0][2], 0, 0, 0);
    acc[0][3] = __builtin_amdgcn_mfma_f32_16x16x32_bf16(a0, b3, acc[0][3], 0, 0, 0);
    acc[1][0] = __builtin_amdgcn_mfma_f32_16x16x32_bf16(a1, b0, acc[1][0], 0, 0, 0);
    acc[1][1] = __builtin_amdgcn_mfma_f32_16x16x32_bf16(a1, b1, acc[1][1], 0, 0, 0);
    acc[1][2] = __builtin_amdgcn_mfma_f32_16x16x32_bf16(a1, b2, acc[1][2], 0, 0, 0);
    acc[1][3] = __builtin_amdgcn_mfma_f32_16x16x32_bf16(a1, b3, acc[1][3], 0, 0, 0);
    __builtin_amdgcn_s_setprio(0);

    if (more) { asm volatile("s_waitcnt vmcnt(2)" ::: "memory"); }
    else      { asm volatile("s_waitcnt vmcnt(0)" ::: "memory"); }
    __builtin_amdgcn_s_barrier();
    asm volatile("" ::: "memory");
    bf16x8 a2 = *(const bf16x8*)(Ac + offA[2]);
    bf16x8 a3 = *(const bf16x8*)(Ac + offA[3]);
    if (more) {
      gload_lds16(gA + rA0 + k1, An + dOff);
      gload_lds16(gA + rA1 + k1, An + 8192 + dOff);
    }
    __builtin_amdgcn_s_setprio(1);
    acc[2][0] = __builtin_amdgcn_mfma_f32_16x16x32_bf16(a2, b0, acc[2][0], 0, 0, 0);
    acc[2][1] = __builtin_amdgcn_mfma_f32_16x16x32_bf16(a2, b1, acc[2][1], 0, 0, 0);
    acc[2][2] = __builtin_amdgcn_mfma_f32_16x16x32_bf16(a2, b2, acc[2][2], 0, 0, 0);
    acc[2][3] = __builtin_amdgcn_mfma_f32_16x16x32_bf16(a2, b3, acc[2][3], 0, 0, 0);
    acc[3][0] = __builtin_amdgcn_mfma_f32_16x16x32_bf16(a3, b0, acc[3][0], 0, 0, 0);
    acc[3][1] = __builtin_amdgcn_mfma_f32_16x16x32_bf16(a3, b1, acc[3][1], 0, 0, 0);
    acc[3][2] = __builtin_amdgcn_mfma_f32_16x16x32_bf16(a3, b2, acc[3][2], 0, 0, 0);
    acc[3][3] = __builtin_amdgcn_mfma_f32_16x16x32_bf16(a3, b3, acc[3][3], 0, 0, 0);
    __builtin_amdgcn_s_setprio(0);
  }

  __syncthreads();
  {
    float* pub = (float*)(smem + wg * 32768);
#pragma unroll
    for (int ii = 0; ii < 2; ++ii) {
      const int ip = wg ? ii : 2 + ii;
#pragma unroll
      for (int j = 0; j < 4; ++j)
#pragma unroll
        for (int r = 0; r < 4; ++r)
          pub[((ii * 4 + j) * 4 + r) * 256 + w2 * 64 + lane] = acc[ip][j][r];
    }
  }
  __syncthreads();
  {
    const float* oth = (const float*)(smem + (wg ^ 1) * 32768);
    const int rb = (lane >> 4) * 4;
    const int cb = lane & 15;
#pragma unroll
    for (int ii = 0; ii < 2; ++ii) {
      const int im = wg ? 2 + ii : ii;
#pragma unroll
      for (int j = 0; j < 4; ++j)
#pragma unroll
        for (int r = 0; r < 4; ++r) {
          float vsum = acc[im][j][r] + oth[((ii * 4 + j) * 4 + r) * 256 + w2 * 64 + lane];
          int row = bm * 128 + wm * 64 + im * 16 + rb + r;
          int col = bn * 128 + wn * 64 + j * 16 + cb;
          Cout[(size_t)row * N + col] = vsum;
        }
    }
  }
}

// ---------------- causal flash attention (MQA), kv-split wave pairs ----------------
// grid (8, B*NH) = 512 blocks (exactly 2/CU). block 512 = 8 waves = 4 pairs.
// Pair p owns 32 q rows; wave hw=w&1 handles kv rows [hw*32, hw*32+32) of each
// 64-row KV tile (independent online softmax; pair-merge via LDS at epilogue).
// Each block processes q-tiles {pr, 15-pr} (balanced: 34 KV rounds/block).
__global__ __launch_bounds__(512) void k_attn(const unsigned short* __restrict__ fused,
                                              const unsigned short* __restrict__ Kr,
                                              const unsigned short* __restrict__ Vt,
                                              unsigned short* __restrict__ ctx) {
  __shared__ unsigned short Ks[2][64 * 64];  // 16 KB, swizzled
  __shared__ unsigned short Vs[2][64 * 64];  // 16 KB, swizzled
  __shared__ float Scr[4][64][34];           // 34 KB pair-merge scratch
  const int tid  = threadIdx.x;
  const int lane = tid & 63;
  const int w    = tid >> 6;      // 0..7
  const int p    = w >> 1;        // pair 0..3
  const int hw   = w & 1;         // kv half
  const int pr   = blockIdx.x;    // 0..7
  const int bh   = blockIdx.y;
  const int b    = bh >> 5;
  const int h    = bh & 31;
  const int ql   = lane & 31;
  const int hi   = lane >> 5;

  const int strow = tid >> 3;                 // 0..63
  const int stch  = tid & 7;
  const int ssc   = (stch ^ (strow & 7)) * 8;
  const size_t kSrc = (size_t)(b * S_ + strow) * HD_ + ssc;
  const size_t vSrc = (size_t)(b * HD_ + strow) * S_ + ssc;
  const int dOff = tid * 16;

  for (int side = 0; side < 2; ++side) {
    const int qt = side ? (15 - pr) : pr;
    const int q0 = qt * 128;
    const int nt = 2 * qt + 2;
    const int qrow  = q0 + p * 32 + ql;
    const int qlo_w = q0 + p * 32;
    const int qhi_w = qlo_w + 31;

    bf16x8 qf[4];
    {
      const unsigned short* qb =
          fused + ((size_t)(b * S_ + qrow)) * FDIM + h * HD_ + hi * 8;
#pragma unroll
      for (int s = 0; s < 4; ++s)
        qf[s] = *reinterpret_cast<const bf16x8*>(qb + s * 16);
    }

    f32x16 oacc0 = {}, oacc1 = {}, lsumv = {};
    float mrun = -1e30f;

    if (side) __syncthreads();

    gload_lds16(Kr + kSrc, (char*)Ks + dOff);
    gload_lds16(Vt + vSrc, (char*)Vs + dOff);

    int buf = 0;
    for (int t = 0; t < nt; ++t) {
      __syncthreads();

      if (t + 1 < nt) {
        const int kv1 = (t + 1) * 64;
        gload_lds16(Kr + kSrc + (size_t)kv1 * HD_, (char*)Ks + (buf ^ 1) * 8192 + dOff);
        gload_lds16(Vt + vSrc + kv1,               (char*)Vs + (buf ^ 1) * 8192 + dOff);
      }

      const int kv0 = t * 64;
      const unsigned short* Kcur = (const unsigned short*)((const char*)Ks + buf * 8192);
      const unsigned short* Vcur = (const unsigned short*)((const char*)Vs + buf * 8192);
      buf ^= 1;

      if (kv0 + hw * 32 > qhi_w) continue;

      f32x16 sh = {};
      __builtin_amdgcn_s_setprio(1);
#pragma unroll
      for (int s = 0; s < 4; ++s) {
        bf16x8 kf = lds_rd_swz(Kcur, hw * 32 + ql, s * 2 + hi);
        sh = __builtin_amdgcn_mfma_f32_32x32x16_bf16(kf, qf[s], sh, 0, 0, 0);
      }
      __builtin_amdgcn_s_setprio(0);

      if (kv0 + hw * 32 + 31 > qlo_w) {
        const int thr = qrow - kv0 - hw * 32 - 4 * hi;
#pragma unroll
        for (int r = 0; r < 16; ++r) {
          const int kvo = (r & 3) + 8 * (r >> 2);
          sh[r] = (kvo <= thr) ? sh[r] : -1e30f;
        }
      }

      float mx;
      {
        float t16[8];
#pragma unroll
        for (int r = 0; r < 8; ++r) t16[r] = fmaxf(sh[r], sh[r + 8]);
#pragma unroll
        for (int st = 4; st >= 1; st >>= 1)
#pragma unroll
          for (int r = 0; r < st; ++r) t16[r] = fmaxf(t16[r], t16[r + st]);
        mx = fmaxf(t16[0], __shfl_xor(t16[0], 32));
      }

      float mcur;
      bool okd = (mx <= mrun + 8.0f);
      if (__all(okd)) {
        mcur = mrun;
      } else {
        float mnew = fmaxf(mrun, mx);
        float corr = __builtin_amdgcn_exp2f(mrun - mnew);
        mrun = mnew; mcur = mnew;
#pragma unroll
        for (int r = 0; r < 16; ++r) {
          oacc0[r] *= corr; oacc1[r] *= corr; lsumv[r] *= corr;
        }
      }

#pragma unroll
      for (int r = 0; r < 16; ++r) {
        sh[r] = __builtin_amdgcn_exp2f(sh[r] - mcur);
        lsumv[r] += sh[r];
      }

      bf16x8 pf[2];
#pragma unroll
      for (int j = 0; j < 2; ++j) {
        uint32_t a0 = pkbf(sh[8 * j + 0], sh[8 * j + 1]);
        uint32_t a1 = pkbf(sh[8 * j + 2], sh[8 * j + 3]);
        uint32_t b0 = pkbf(sh[8 * j + 4], sh[8 * j + 5]);
        uint32_t b1 = pkbf(sh[8 * j + 6], sh[8 * j + 7]);
        uint32_t s0 = hi ? a0 : b0;
        uint32_t s1 = hi ? a1 : b1;
        uint32_t r0 = __shfl_xor(s0, 32);
        uint32_t r1 = __shfl_xor(s1, 32);
        union { uint32_t wd[4]; bf16x8 v; } bw;
        bw.wd[0] = hi ? r0 : a0;
        bw.wd[1] = hi ? r1 : a1;
        bw.wd[2] = hi ? b0 : r0;
        bw.wd[3] = hi ? b1 : r1;
        pf[j] = bw.v;
      }

      __builtin_amdgcn_s_setprio(1);
#pragma unroll
      for (int j = 0; j < 2; ++j) {
        bf16x8 vf0 = lds_rd_swz(Vcur, ql,      hw * 4 + j * 2 + hi);
        bf16x8 vf1 = lds_rd_swz(Vcur, 32 + ql, hw * 4 + j * 2 + hi);
        oacc0 = __builtin_amdgcn_mfma_f32_32x32x16_bf16(vf0, pf[j], oacc0, 0, 0, 0);
        oacc1 = __builtin_amdgcn_mfma_f32_32x32x16_bf16(vf1, pf[j], oacc1, 0, 0, 0);
      }
      __builtin_amdgcn_s_setprio(0);
    }

    float lw;
    {
      float t16[8];
#pragma unroll
      for (int r = 0; r < 8; ++r) t16[r] = lsumv[r] + lsumv[r + 8];
#pragma unroll
      for (int st = 4; st >= 1; st >>= 1)
#pragma unroll
        for (int r = 0; r < st; ++r) t16[r] += t16[r + st];
      lw = t16[0] + __shfl_xor(t16[0], 32);
    }

    if (hw) {
      float* sp = &Scr[p][lane][0];
#pragma unroll
      for (int r = 0; r < 16; ++r) { sp[r] = oacc0[r]; sp[16 + r] = oacc1[r]; }
      sp[32] = mrun; sp[33] = lw;
    }
    __syncthreads();
    if (!hw) {
      const float* sp = &Scr[p][lane][0];
      float m1 = sp[32], l1 = sp[33];
      float m  = fmaxf(mrun, m1);
      float c0 = __builtin_amdgcn_exp2f(mrun - m);
      float c1 = __builtin_amdgcn_exp2f(m1 - m);
      float inv = 1.0f / (lw * c0 + l1 * c1);
      unsigned short* cb = ctx + ((size_t)(b * S_ + qrow)) * HID_ + h * HD_;
#pragma unroll
      for (int dblk = 0; dblk < 2; ++dblk) {
#pragma unroll
        for (int r = 0; r < 16; r += 2) {
          float own0 = dblk ? oacc1[r]     : oacc0[r];
          float own1 = dblk ? oacc1[r + 1] : oacc0[r + 1];
          float e0 = (own0 * c0 + sp[dblk * 16 + r]     * c1) * inv;
          float e1 = (own1 * c0 + sp[dblk * 16 + r + 1] * c1) * inv;
          int d = dblk * 32 + (r & 3) + 8 * (r >> 2) + 4 * hi;
          *reinterpret_cast<uint32_t*>(cb + d) = pkbf(e0, e1);
        }
      }
    }
  }
}

// ---------------- launch ----------------
extern "C" void kernel_launch(void* const* d_in, const int* in_sizes, int n_in,
                              void* d_out, int out_size, void* d_ws, size_t ws_size,
                              hipStream_t stream) {
  const float* hidden  = (const float*)d_in[0];
  const float* w_qkv   = (const float*)d_in[1];
  const float* w_dense = (const float*)d_in[2];
  char* ws = (char*)d_ws;

  // workspace layout (bytes)
  unsigned short* Xb  = (unsigned short*)(ws + 0);          // 4096x2048 bf16 (reused as ctx)
  unsigned short* Wqb = (unsigned short*)(ws + 16777216);   // 2176x2048 bf16
  unsigned short* Wdb = (unsigned short*)(ws + 25690112);   // 2048x2048 bf16
  unsigned short* Fb  = (unsigned short*)(ws + 34078720);   // 4096x2176 bf16 (fused QKV)
  unsigned short* Kr  = (unsigned short*)(ws + 51904512);   // 2x2048x64 bf16
  unsigned short* Vt  = (unsigned short*)(ws + 52428800);   // 2x64x2048 bf16

  // all three fp32->bf16 converts in one launch
  const int nq = N1Q + N2Q + N3Q;   // 4259840 float4 groups
  k_cvt_all<<<dim3((nq + 255) / 256), 256, 0, stream>>>(
      hidden, w_qkv, w_dense, Xb, Wqb, Wdb);

  // fused = X @ Wqkv^T with fused RoPE epilogue. grid (17,16) = 272, XCD-swizzled
  k_gemm1<<<dim3(FDIM / 128, (B_ * S_) / 256), 512, 0, stream>>>(
      Xb, Wqb, Fb, Kr, Vt, B_ * S_, FDIM, HID_);

  // attention -> ctx (reuses Xb)
  k_attn<<<dim3(8, B_ * NH_), 512, 0, stream>>>(Fb, Kr, Vt, Xb);

  // out = ctx @ Wd^T, fp32. grid (16,32) = 512 = exactly 2 blocks/CU, XCD-swizzled
  k_gemm2<<<dim3(HID_ / 128, (B_ * S_) / 128), 512, 0, stream>>>(
      Xb, Wdb, (float*)d_out, B_ * S_, HID_, HID_);
}